// Round 4
// baseline (239.569 us; speedup 1.0000x reference)
//
#include <hip/hip_runtime.h>
#include <hip/hip_bf16.h>

#define B_  4
#define C_  64
#define C8_ 8
#define N_  9216   // 96*96
#define NEG_LOG2E (-1.44269504088896340736f)

typedef _Float16 half8  __attribute__((ext_vector_type(8)));
typedef float    f32x16 __attribute__((ext_vector_type(16)));

static __device__ __forceinline__ float fast_exp2(float x){ float r; asm("v_exp_f32 %0, %1":"=v"(r):"v"(x)); return r; }
static __device__ __forceinline__ float fast_rcp (float x){ float r; asm("v_rcp_f32 %0, %1":"=v"(r):"v"(x)); return r; }

static __device__ __forceinline__ void gload16(const void* g, void* l){
    __builtin_amdgcn_global_load_lds((const __attribute__((address_space(1))) void*)g,
                                     (__attribute__((address_space(3))) void*)l, 16, 0, 0);
}

// ---------------- Kernel 1: QKV 1x1 convs -> f16 Qt/Kt (n-major, x8) + Vperm ----------------
// grid (N/128, B), block 256
__global__ void qkv_kernel(const float* __restrict__ x,
                           const float* __restrict__ wq, const float* __restrict__ bq,
                           const float* __restrict__ wk, const float* __restrict__ bk,
                           const float* __restrict__ wv, const float* __restrict__ bv,
                           _Float16* __restrict__ Qt, _Float16* __restrict__ Kt,
                           _Float16* __restrict__ Vp) {
    __shared__ float xl[C_ * 128];
    __shared__ float wl[80 * C_];
    __shared__ float bl[80];
    const int bi = blockIdx.y;
    const int n0 = blockIdx.x * 128;
    const int tid = threadIdx.x;

    for (int i = tid; i < C_ * 128; i += 256) {
        int c = i >> 7, n = i & 127;
        xl[i] = x[(size_t)(bi * C_ + c) * N_ + n0 + n];
    }
    for (int i = tid; i < 80 * C_; i += 256) {
        wl[i] = (i < 512) ? wq[i] : (i < 1024) ? wk[i - 512] : wv[i - 1024];
    }
    if (tid < 80) bl[tid] = (tid < 8) ? bq[tid] : (tid < 16) ? bk[tid - 8] : bv[tid - 16];
    __syncthreads();

    const int n = tid & 127;
    const int g = tid >> 7;
    const int nn = n0 + n;
    // V m-permutation: within each 16-group swap chunks [4..7] <-> [8..11]
    const int low = nn & 15;
    const int g2 = (low >> 2) & 3;
    const int low2 = (g2 == 1) ? low + 4 : (g2 == 2) ? low - 4 : low;
    const int posn = (nn & ~15) | low2;

    for (int k = 0; k < 40; k += 4) {
        const int o = g * 40 + k;
        float a0 = bl[o], a1 = bl[o + 1], a2 = bl[o + 2], a3 = bl[o + 3];
        #pragma unroll 16
        for (int c = 0; c < C_; ++c) {
            float xv = xl[c * 128 + n];
            a0 += xv * wl[(o + 0) * C_ + c];
            a1 += xv * wl[(o + 1) * C_ + c];
            a2 += xv * wl[(o + 2) * C_ + c];
            a3 += xv * wl[(o + 3) * C_ + c];
        }
        if (o < 8) {               // Q: fold -log2(e) for sigmoid-via-exp2
            _Float16* dst = Qt + ((size_t)(bi * N_) + nn) * 8 + o;
            dst[0] = (_Float16)(a0 * NEG_LOG2E); dst[1] = (_Float16)(a1 * NEG_LOG2E);
            dst[2] = (_Float16)(a2 * NEG_LOG2E); dst[3] = (_Float16)(a3 * NEG_LOG2E);
        } else if (o < 16) {       // K
            _Float16* dst = Kt + ((size_t)(bi * N_) + nn) * 8 + (o - 8);
            dst[0] = (_Float16)a0; dst[1] = (_Float16)a1;
            dst[2] = (_Float16)a2; dst[3] = (_Float16)a3;
        } else {                   // V (m-permuted layout)
            const int c0 = o - 16;
            Vp[(size_t)(bi * C_ + c0 + 0) * N_ + posn] = (_Float16)a0;
            Vp[(size_t)(bi * C_ + c0 + 1) * N_ + posn] = (_Float16)a1;
            Vp[(size_t)(bi * C_ + c0 + 2) * N_ + posn] = (_Float16)a2;
            Vp[(size_t)(bi * C_ + c0 + 3) * N_ + posn] = (_Float16)a3;
        }
    }
}

// ---------------- Kernel 2: fused MFMA sigmoid-attention -> partials ----------------
// grid (N/128, 2 m-halves, B), block 256 (4 waves; wave owns 32 n-cols, all 64 c)
#define VOFF 0                 // 2 x 8192 B  (V tile [c 0..63][64 m] f16, chunk-XOR swizzled)
#define KOFF 16384             // 2 x 1024 B  (K tile [m 0..63][8 c] f16)
#define QOFF 18432             // 2048 B      (Q tile [n 0..127][8 c] f16)
#define ZOFF 20480             // 16 B zero pad
#define LDSBYTES 20608

#define STAGE(mt, bsel) do {                                                            \
    const int m0s_ = mbase + (mt) * 64;                                                 \
    if (wave == 0)                                                                      \
        gload16(Kt + ((size_t)(b * N_ + m0s_) + lane) * 8, lds + KOFF + (bsel) * 1024); \
    {                                                                                   \
        const int ld0_ = wave * 2;                                                      \
        const int cl0_ = ld0_ * 8 + (lane >> 3);                                        \
        const int q0_  = (lane & 7) ^ (cl0_ & 7);                                       \
        gload16(Vp + (size_t)(b * C_ + cl0_) * N_ + m0s_ + q0_ * 8,                     \
                lds + VOFF + (bsel) * 8192 + ld0_ * 1024);                              \
        const int cl1_ = cl0_ + 8;                                                      \
        const int q1_  = (lane & 7) ^ (cl1_ & 7);                                       \
        gload16(Vp + (size_t)(b * C_ + cl1_) * N_ + m0s_ + q1_ * 8,                     \
                lds + VOFF + (bsel) * 8192 + (ld0_ + 1) * 1024);                        \
    } } while (0)

__global__ __launch_bounds__(256) void attn_kernel(
        const _Float16* __restrict__ Qt, const _Float16* __restrict__ Kt,
        const _Float16* __restrict__ Vp, float* __restrict__ part) {
    __shared__ ulong2 ldsq[LDSBYTES / 16];
    char* lds = (char*)ldsq;
    const int tid  = threadIdx.x;
    const int wave = tid >> 6, lane = tid & 63;
    const int l31  = lane & 31;
    const int hi   = lane >> 5;
    const int b    = blockIdx.z, mh = blockIdx.y;
    const int n0   = blockIdx.x * 128;
    const int mbase = mh * (N_ / 2);

    if (tid < 8) ((short*)(lds + ZOFF))[tid] = 0;

    STAGE(0, 0);
    if (wave == 1) {
        gload16(Qt + ((size_t)(b * N_ + n0) + lane) * 8,      lds + QOFF);
        gload16(Qt + ((size_t)(b * N_ + n0 + 64) + lane) * 8, lds + QOFF + 1024);
    }
    __syncthreads();

    const int qa = (lane < 32) ? (QOFF + (wave * 32 + l31) * 16) : ZOFF;
    const half8 qf = *(const half8*)(lds + qa);

    f32x16 acc0 = (f32x16)(0.f), acc1 = (f32x16)(0.f);

    for (int t = 0; t < 72; ++t) {
        const int buf = t & 1;
        if (t + 1 < 72) STAGE(t + 1, buf ^ 1);

        // ---- energy: S[m][n] = sum_c K[m][c] * Q'[c][n]  (k-slots 8..15 zero) ----
        const int ka0 = (lane < 32) ? (KOFF + buf * 1024 +       l31 * 16) : ZOFF;
        const int ka1 = (lane < 32) ? (KOFF + buf * 1024 + 512 + l31 * 16) : ZOFF;
        const half8 kf0 = *(const half8*)(lds + ka0);
        const half8 kf1 = *(const half8*)(lds + ka1);
        f32x16 s0 = __builtin_amdgcn_mfma_f32_32x32x16_f16(kf0, qf, (f32x16)(0.f), 0, 0, 0);
        f32x16 s1 = __builtin_amdgcn_mfma_f32_32x32x16_f16(kf1, qf, (f32x16)(0.f), 0, 0, 0);

        // ---- att = sigmoid = 1/(1+2^S')  (S' pre-scaled by -log2e via Q) ----
        #pragma unroll
        for (int r = 0; r < 16; ++r) s0[r] = fast_rcp(1.f + fast_exp2(s0[r]));
        #pragma unroll
        for (int r = 0; r < 16; ++r) s1[r] = fast_rcp(1.f + fast_exp2(s1[r]));

        // ---- PV: acc[c][n] += V[c][m] * att[m][n], k-map matched to C/D row layout ----
        const int vbase = VOFF + buf * 8192;
        #pragma unroll
        for (int ks = 0; ks < 4; ++ks) {
            f32x16 am = (ks < 2) ? s0 : s1;
            const int bb = (ks & 1) * 8;
            uint4 pk;
            pk.x = __builtin_bit_cast(unsigned int, __builtin_amdgcn_cvt_pkrtz(am[bb + 0], am[bb + 1]));
            pk.y = __builtin_bit_cast(unsigned int, __builtin_amdgcn_cvt_pkrtz(am[bb + 2], am[bb + 3]));
            pk.z = __builtin_bit_cast(unsigned int, __builtin_amdgcn_cvt_pkrtz(am[bb + 4], am[bb + 5]));
            pk.w = __builtin_bit_cast(unsigned int, __builtin_amdgcn_cvt_pkrtz(am[bb + 6], am[bb + 7]));
            const half8 bf = __builtin_bit_cast(half8, pk);
            const int sw = ((2 * ks + hi) ^ (l31 & 7)) * 16;
            const half8 af0 = *(const half8*)(lds + vbase + l31 * 128 + sw);
            const half8 af1 = *(const half8*)(lds + vbase + (32 + l31) * 128 + sw);
            acc0 = __builtin_amdgcn_mfma_f32_32x32x16_f16(af0, bf, acc0, 0, 0, 0);
            acc1 = __builtin_amdgcn_mfma_f32_32x32x16_f16(af1, bf, acc1, 0, 0, 0);
        }
        __syncthreads();
    }

    float* pp = part + ((size_t)(mh * B_ + b) * C_) * (size_t)N_ + n0 + wave * 32 + l31;
    #pragma unroll
    for (int r = 0; r < 16; ++r) {
        const int c0 = (r & 3) + 8 * (r >> 2) + 4 * hi;
        pp[(size_t)c0 * N_]        = acc0[r];
        pp[(size_t)(c0 + 32) * N_] = acc1[r];
    }
}

// ---------------- Kernel 3: partials + residual -> out, fused avg/max pool ----------------
// grid (C, B), block 256
__global__ void reduce_pool(const float* __restrict__ part, const float* __restrict__ x,
                            float* __restrict__ outp,
                            float* __restrict__ avgP, float* __restrict__ maxP) {
    const int c = blockIdx.x, b = blockIdx.y;
    const size_t off = (size_t)(b * C_ + c) * N_;
    const float4* p0 = (const float4*)(part + ((size_t)(0 * B_ + b) * C_ + c) * N_);
    const float4* p1 = (const float4*)(part + ((size_t)(1 * B_ + b) * C_ + c) * N_);
    const float4* xr = (const float4*)(x + off);
    float4* orow = (float4*)(outp + off);
    const int tid = threadIdx.x;
    float s = 0.f, mx = -3.4e38f;
    for (int i = tid; i < N_ / 4; i += 256) {
        float4 a = p0[i], bq = p1[i], xv = xr[i];
        float4 o;
        o.x = a.x + bq.x + xv.x; o.y = a.y + bq.y + xv.y;
        o.z = a.z + bq.z + xv.z; o.w = a.w + bq.w + xv.w;
        orow[i] = o;
        s += o.x + o.y + o.z + o.w;
        mx = fmaxf(mx, fmaxf(fmaxf(o.x, o.y), fmaxf(o.z, o.w)));
    }
    #pragma unroll
    for (int offm = 32; offm > 0; offm >>= 1) {
        s += __shfl_down(s, offm, 64);
        mx = fmaxf(mx, __shfl_down(mx, offm, 64));
    }
    __shared__ float ss[4], sm[4];
    if ((tid & 63) == 0) { ss[tid >> 6] = s; sm[tid >> 6] = mx; }
    __syncthreads();
    if (tid == 0) {
        float fs = ss[0] + ss[1] + ss[2] + ss[3];
        float fm = fmaxf(fmaxf(sm[0], sm[1]), fmaxf(sm[2], sm[3]));
        avgP[b * C_ + c] = fs / (float)N_;
        maxP[b * C_ + c] = fm;
    }
}

// ---------------- Kernel 4: CBAM MLP + sigmoid scale ----------------
__global__ void mlp_kernel(const float* __restrict__ avgP, const float* __restrict__ maxP,
                           const float* __restrict__ w1, const float* __restrict__ w2,
                           float* __restrict__ scaleP) {
    __shared__ float h[32];
    const int tid = threadIdx.x;
    if (tid < 32) {
        int b = tid >> 3, r = (tid >> 1) & 3, wh = tid & 1;
        const float* src = wh ? maxP : avgP;
        float s = 0.f;
        for (int c = 0; c < C_; ++c) s += src[b * C_ + c] * w1[r * C_ + c];
        h[tid] = fmaxf(s, 0.f);
    }
    __syncthreads();
    int b = tid >> 6, c = tid & 63;
    float s = 0.f;
    #pragma unroll
    for (int r = 0; r < 4; ++r)
        s += (h[b * 8 + r * 2] + h[b * 8 + r * 2 + 1]) * w2[c * 4 + r];
    scaleP[tid] = fast_rcp(1.f + fast_exp2(s * NEG_LOG2E));
}

// ---------------- Kernel 5: apply channel scale in place ----------------
__global__ void scale_kernel(float* __restrict__ outp, const float* __restrict__ scaleP) {
    int i4 = blockIdx.x * 256 + threadIdx.x;
    float sc = scaleP[i4 / (N_ / 4)];
    float4 v = *(const float4*)&outp[(size_t)i4 * 4];
    v.x *= sc; v.y *= sc; v.z *= sc; v.w *= sc;
    *(float4*)&outp[(size_t)i4 * 4] = v;
}

extern "C" void kernel_launch(void* const* d_in, const int* in_sizes, int n_in,
                              void* d_out, int out_size, void* d_ws, size_t ws_size,
                              hipStream_t stream) {
    const float* x  = (const float*)d_in[0];
    const float* wq = (const float*)d_in[1];
    const float* bq = (const float*)d_in[2];
    const float* wk = (const float*)d_in[3];
    const float* bk = (const float*)d_in[4];
    const float* wv = (const float*)d_in[5];
    const float* bv = (const float*)d_in[6];
    const float* w1 = (const float*)d_in[7];
    const float* w2 = (const float*)d_in[8];
    float* outp = (float*)d_out;

    char* w = (char*)d_ws;
    _Float16* Qt = (_Float16*)(w);                       // B*N*8 f16   = 589824 B
    _Float16* Kt = (_Float16*)(w + 589824);              // B*N*8 f16   = 589824 B
    _Float16* Vp = (_Float16*)(w + 1179648);             // B*C*N f16   = 4718592 B
    float* part  = (float*)(w + 5898240);                // 2*B*C*N f32 = 18874368 B
    float* avgP  = (float*)(w + 24772608);
    float* maxP  = avgP + 256;
    float* scaleP = maxP + 256;

    qkv_kernel<<<dim3(N_ / 128, B_), 256, 0, stream>>>(x, wq, bq, wk, bk, wv, bv, Qt, Kt, Vp);
    attn_kernel<<<dim3(N_ / 128, 2, B_), 256, 0, stream>>>(Qt, Kt, Vp, part);
    reduce_pool<<<dim3(C_, B_), 256, 0, stream>>>(part, x, outp, avgP, maxP);
    mlp_kernel<<<1, 256, 0, stream>>>(avgP, maxP, w1, w2, scaleP);
    scale_kernel<<<(B_ * C_ * N_ / 4) / 256, 256, 0, stream>>>(outp, scaleP);
}

// Round 10
// 210.661 us; speedup vs baseline: 1.1372x; 1.1372x over previous
//
#include <hip/hip_runtime.h>
#include <hip/hip_bf16.h>

#define B_  4
#define C_  64
#define C8_ 8
#define N_  9216   // 96*96
#define BN  128    // query tile per block
#define BM  64     // key/value tile per iteration
#define MSPLIT 4
#define MCHUNK (N_ / MSPLIT)   // 2304
#define NITER  (MCHUNK / BM)   // 36
#define NEG_LOG2E (-1.44269504088896340736f)

typedef _Float16 half8  __attribute__((ext_vector_type(8)));
typedef float    f32x16 __attribute__((ext_vector_type(16)));

static __device__ __forceinline__ float fast_exp2(float x){ float r; asm("v_exp_f32 %0, %1":"=v"(r):"v"(x)); return r; }
static __device__ __forceinline__ float fast_rcp (float x){ float r; asm("v_rcp_f32 %0, %1":"=v"(r):"v"(x)); return r; }

static __device__ __forceinline__ void gload16(const void* g, void* l){
    __builtin_amdgcn_global_load_lds((const __attribute__((address_space(1))) void*)g,
                                     (__attribute__((address_space(3))) void*)l, 16, 0, 0);
}

// ---------------- Kernel 1: QKV via MFMA: out[o][n] = W[o][c] x[c][n] ----------------
// grid (N/128, B), block 256; wave w owns 32 n-cols, all 96 (80 used) out-rows
__global__ __launch_bounds__(256) void qkv2_kernel(
        const float* __restrict__ x,
        const float* __restrict__ wq, const float* __restrict__ bq,
        const float* __restrict__ wk, const float* __restrict__ bk,
        const float* __restrict__ wv, const float* __restrict__ bv,
        _Float16* __restrict__ Qt, _Float16* __restrict__ Kt,
        _Float16* __restrict__ Vp) {
    const int tid = threadIdx.x;
    const int wv_i = tid >> 6, lane = tid & 63, l31 = lane & 31, hi = lane >> 5;
    const int b = blockIdx.y;
    const int n = blockIdx.x * 128 + wv_i * 32 + l31;

    // A-fragments: W rows (Q rows pre-scaled by -log2e), zero-padded rows 80..95
    half8 af[3][4];
    #pragma unroll
    for (int mt = 0; mt < 3; ++mt) {
        const int o = mt * 32 + l31;
        #pragma unroll
        for (int kk = 0; kk < 4; ++kk) {
            half8 a;
            #pragma unroll
            for (int j = 0; j < 8; ++j) {
                const int c = kk * 16 + hi * 8 + j;
                float v = 0.f;
                if (o < 8)       v = wq[o * C_ + c] * NEG_LOG2E;
                else if (o < 16) v = wk[(o - 8) * C_ + c];
                else if (o < 80) v = wv[(o - 16) * C_ + c];
                a[j] = (_Float16)v;
            }
            af[mt][kk] = a;
        }
    }
    // B-fragments: x columns (coalesced 32-lane row reads)
    half8 bf[4];
    #pragma unroll
    for (int kk = 0; kk < 4; ++kk) {
        half8 t;
        #pragma unroll
        for (int j = 0; j < 8; ++j) {
            const int c = kk * 16 + hi * 8 + j;
            t[j] = (_Float16)x[(size_t)(b * C_ + c) * N_ + n];
        }
        bf[kk] = t;
    }
    // V m-permutation of n (within 16-group swap chunks [4..7]<->[8..11])
    const int low = n & 15;
    const int g2 = (low >> 2) & 3;
    const int low2 = (g2 == 1) ? low + 4 : (g2 == 2) ? low - 4 : low;
    const int posn = (n & ~15) | low2;

    #pragma unroll
    for (int mt = 0; mt < 3; ++mt) {
        f32x16 acc = (f32x16)(0.f);
        #pragma unroll
        for (int kk = 0; kk < 4; ++kk)
            acc = __builtin_amdgcn_mfma_f32_32x32x16_f16(af[mt][kk], bf[kk], acc, 0, 0, 0);
        #pragma unroll
        for (int r = 0; r < 16; ++r) {
            const int o = mt * 32 + (r & 3) + 8 * (r >> 2) + 4 * hi;
            if (o < 8)
                Qt[((size_t)(b * N_) + n) * 8 + o] = (_Float16)(acc[r] + bq[o] * NEG_LOG2E);
            else if (o < 16)
                Kt[((size_t)(b * N_) + n) * 8 + (o - 8)] = (_Float16)(acc[r] + bk[o - 8]);
            else if (o < 80)
                Vp[(size_t)(b * C_ + (o - 16)) * N_ + posn] = (_Float16)(acc[r] + bv[o - 16]);
        }
    }
}

// ---------------- Kernel 2: fused MFMA sigmoid-attention -> partials ----------------
// grid (N/128, MSPLIT, B), block 256 (4 waves; wave owns 32 n-cols, all 64 c)
// VALIDATED round-4 structure; only the m-range per block changed (2304, 36 iters).
#define VOFF 0                 // 2 x 8192 B  (V tile [c 0..63][64 m] f16, chunk-XOR swizzled)
#define KOFF 16384             // 2 x 1024 B  (K tile [m 0..63][8 c] f16)
#define QOFF 18432             // 2048 B      (Q tile [n 0..127][8 c] f16)
#define ZOFF 20480             // 16 B zero pad
#define LDSBYTES 20608

#define STAGE(mt, bsel) do {                                                            \
    const int m0s_ = mbase + (mt) * 64;                                                 \
    if (wave == 0)                                                                      \
        gload16(Kt + ((size_t)(b * N_ + m0s_) + lane) * 8, lds + KOFF + (bsel) * 1024); \
    {                                                                                   \
        const int ld0_ = wave * 2;                                                      \
        const int cl0_ = ld0_ * 8 + (lane >> 3);                                        \
        const int q0_  = (lane & 7) ^ (cl0_ & 7);                                       \
        gload16(Vp + (size_t)(b * C_ + cl0_) * N_ + m0s_ + q0_ * 8,                     \
                lds + VOFF + (bsel) * 8192 + ld0_ * 1024);                              \
        const int cl1_ = cl0_ + 8;                                                      \
        const int q1_  = (lane & 7) ^ (cl1_ & 7);                                       \
        gload16(Vp + (size_t)(b * C_ + cl1_) * N_ + m0s_ + q1_ * 8,                     \
                lds + VOFF + (bsel) * 8192 + (ld0_ + 1) * 1024);                        \
    } } while (0)

__global__ __launch_bounds__(256) void attn_kernel(
        const _Float16* __restrict__ Qt, const _Float16* __restrict__ Kt,
        const _Float16* __restrict__ Vp, float* __restrict__ part) {
    __shared__ ulong2 ldsq[LDSBYTES / 16];
    char* lds = (char*)ldsq;
    const int tid  = threadIdx.x;
    const int wave = tid >> 6, lane = tid & 63;
    const int l31  = lane & 31;
    const int hi   = lane >> 5;
    const int b    = blockIdx.z, mh = blockIdx.y;
    const int n0   = blockIdx.x * 128;
    const int mbase = mh * MCHUNK;

    if (tid < 8) ((short*)(lds + ZOFF))[tid] = 0;

    STAGE(0, 0);
    if (wave == 1) {
        gload16(Qt + ((size_t)(b * N_ + n0) + lane) * 8,      lds + QOFF);
        gload16(Qt + ((size_t)(b * N_ + n0 + 64) + lane) * 8, lds + QOFF + 1024);
    }
    __syncthreads();

    const int qa = (lane < 32) ? (QOFF + (wave * 32 + l31) * 16) : ZOFF;
    const half8 qf = *(const half8*)(lds + qa);

    f32x16 acc0 = (f32x16)(0.f), acc1 = (f32x16)(0.f);

    for (int t = 0; t < NITER; ++t) {
        const int buf = t & 1;
        if (t + 1 < NITER) STAGE(t + 1, buf ^ 1);

        // ---- energy: S[m][n] = sum_c K[m][c] * Q'[c][n]  (k-slots 8..15 zero) ----
        const int ka0 = (lane < 32) ? (KOFF + buf * 1024 +       l31 * 16) : ZOFF;
        const int ka1 = (lane < 32) ? (KOFF + buf * 1024 + 512 + l31 * 16) : ZOFF;
        const half8 kf0 = *(const half8*)(lds + ka0);
        const half8 kf1 = *(const half8*)(lds + ka1);
        f32x16 s0 = __builtin_amdgcn_mfma_f32_32x32x16_f16(kf0, qf, (f32x16)(0.f), 0, 0, 0);
        f32x16 s1 = __builtin_amdgcn_mfma_f32_32x32x16_f16(kf1, qf, (f32x16)(0.f), 0, 0, 0);

        // ---- att = sigmoid = 1/(1+2^S')  (S' pre-scaled by -log2e via Q) ----
        #pragma unroll
        for (int r = 0; r < 16; ++r) s0[r] = fast_rcp(1.f + fast_exp2(s0[r]));
        #pragma unroll
        for (int r = 0; r < 16; ++r) s1[r] = fast_rcp(1.f + fast_exp2(s1[r]));

        // ---- PV: acc[c][n] += V[c][m] * att[m][n], k-map matched to C/D row layout ----
        const int vbase = VOFF + buf * 8192;
        #pragma unroll
        for (int ks = 0; ks < 4; ++ks) {
            f32x16 am = (ks < 2) ? s0 : s1;
            const int bb = (ks & 1) * 8;
            uint4 pk;
            pk.x = __builtin_bit_cast(unsigned int, __builtin_amdgcn_cvt_pkrtz(am[bb + 0], am[bb + 1]));
            pk.y = __builtin_bit_cast(unsigned int, __builtin_amdgcn_cvt_pkrtz(am[bb + 2], am[bb + 3]));
            pk.z = __builtin_bit_cast(unsigned int, __builtin_amdgcn_cvt_pkrtz(am[bb + 4], am[bb + 5]));
            pk.w = __builtin_bit_cast(unsigned int, __builtin_amdgcn_cvt_pkrtz(am[bb + 6], am[bb + 7]));
            const half8 bf = __builtin_bit_cast(half8, pk);
            const int sw = ((2 * ks + hi) ^ (l31 & 7)) * 16;
            const half8 af0 = *(const half8*)(lds + vbase + l31 * 128 + sw);
            const half8 af1 = *(const half8*)(lds + vbase + (32 + l31) * 128 + sw);
            acc0 = __builtin_amdgcn_mfma_f32_32x32x16_f16(af0, bf, acc0, 0, 0, 0);
            acc1 = __builtin_amdgcn_mfma_f32_32x32x16_f16(af1, bf, acc1, 0, 0, 0);
        }
        __syncthreads();
    }

    float* pp = part + ((size_t)(mh * B_ + b) * C_) * (size_t)N_ + n0 + wave * 32 + l31;
    #pragma unroll
    for (int r = 0; r < 16; ++r) {
        const int c0 = (r & 3) + 8 * (r >> 2) + 4 * hi;
        pp[(size_t)c0 * N_]        = acc0[r];
        pp[(size_t)(c0 + 32) * N_] = acc1[r];
    }
}

// ---------------- Kernel 3: 4 partials + residual -> out, fused avg/max pool ----------------
// grid (C, B), block 256
__global__ void reduce_pool(const float* __restrict__ part, const float* __restrict__ x,
                            float* __restrict__ outp,
                            float* __restrict__ avgP, float* __restrict__ maxP) {
    const int c = blockIdx.x, b = blockIdx.y;
    const size_t off = (size_t)(b * C_ + c) * N_;
    const float4* p0 = (const float4*)(part + ((size_t)(0 * B_ + b) * C_ + c) * N_);
    const float4* p1 = (const float4*)(part + ((size_t)(1 * B_ + b) * C_ + c) * N_);
    const float4* p2 = (const float4*)(part + ((size_t)(2 * B_ + b) * C_ + c) * N_);
    const float4* p3 = (const float4*)(part + ((size_t)(3 * B_ + b) * C_ + c) * N_);
    const float4* xr = (const float4*)(x + off);
    float4* orow = (float4*)(outp + off);
    const int tid = threadIdx.x;
    float s = 0.f, mx = -3.4e38f;
    for (int i = tid; i < N_ / 4; i += 256) {
        float4 a = p0[i], bq = p1[i], cq = p2[i], dq = p3[i], xv = xr[i];
        float4 o;
        o.x = a.x + bq.x + cq.x + dq.x + xv.x;
        o.y = a.y + bq.y + cq.y + dq.y + xv.y;
        o.z = a.z + bq.z + cq.z + dq.z + xv.z;
        o.w = a.w + bq.w + cq.w + dq.w + xv.w;
        orow[i] = o;
        s += o.x + o.y + o.z + o.w;
        mx = fmaxf(mx, fmaxf(fmaxf(o.x, o.y), fmaxf(o.z, o.w)));
    }
    #pragma unroll
    for (int offm = 32; offm > 0; offm >>= 1) {
        s += __shfl_down(s, offm, 64);
        mx = fmaxf(mx, __shfl_down(mx, offm, 64));
    }
    __shared__ float ss[4], sm[4];
    if ((tid & 63) == 0) { ss[tid >> 6] = s; sm[tid >> 6] = mx; }
    __syncthreads();
    if (tid == 0) {
        float fs = ss[0] + ss[1] + ss[2] + ss[3];
        float fm = fmaxf(fmaxf(sm[0], sm[1]), fmaxf(sm[2], sm[3]));
        avgP[b * C_ + c] = fs / (float)N_;
        maxP[b * C_ + c] = fm;
    }
}

// ---------------- Kernel 4: CBAM MLP + sigmoid scale ----------------
__global__ void mlp_kernel(const float* __restrict__ avgP, const float* __restrict__ maxP,
                           const float* __restrict__ w1, const float* __restrict__ w2,
                           float* __restrict__ scaleP) {
    __shared__ float h[32];
    const int tid = threadIdx.x;
    if (tid < 32) {
        int b = tid >> 3, r = (tid >> 1) & 3, wh = tid & 1;
        const float* src = wh ? maxP : avgP;
        float s = 0.f;
        for (int c = 0; c < C_; ++c) s += src[b * C_ + c] * w1[r * C_ + c];
        h[tid] = fmaxf(s, 0.f);
    }
    __syncthreads();
    int b = tid >> 6, c = tid & 63;
    float s = 0.f;
    #pragma unroll
    for (int r = 0; r < 4; ++r)
        s += (h[b * 8 + r * 2] + h[b * 8 + r * 2 + 1]) * w2[c * 4 + r];
    scaleP[tid] = fast_rcp(1.f + fast_exp2(s * NEG_LOG2E));
}

// ---------------- Kernel 5: apply channel scale in place ----------------
__global__ void scale_kernel(float* __restrict__ outp, const float* __restrict__ scaleP) {
    int i4 = blockIdx.x * 256 + threadIdx.x;
    float sc = scaleP[i4 / (N_ / 4)];
    float4 v = *(const float4*)&outp[(size_t)i4 * 4];
    v.x *= sc; v.y *= sc; v.z *= sc; v.w *= sc;
    *(float4*)&outp[(size_t)i4 * 4] = v;
}

extern "C" void kernel_launch(void* const* d_in, const int* in_sizes, int n_in,
                              void* d_out, int out_size, void* d_ws, size_t ws_size,
                              hipStream_t stream) {
    const float* x  = (const float*)d_in[0];
    const float* wq = (const float*)d_in[1];
    const float* bq = (const float*)d_in[2];
    const float* wk = (const float*)d_in[3];
    const float* bk = (const float*)d_in[4];
    const float* wv = (const float*)d_in[5];
    const float* bv = (const float*)d_in[6];
    const float* w1 = (const float*)d_in[7];
    const float* w2 = (const float*)d_in[8];
    float* outp = (float*)d_out;

    char* w = (char*)d_ws;
    _Float16* Qt = (_Float16*)(w);                       // B*N*8 f16   = 589824 B
    _Float16* Kt = (_Float16*)(w + 589824);              // B*N*8 f16   = 589824 B
    _Float16* Vp = (_Float16*)(w + 1179648);             // B*C*N f16   = 4718592 B
    float* part  = (float*)(w + 5898240);                // MSPLIT*B*C*N f32 = 37748736 B
    float* avgP  = (float*)(w + 43646976);
    float* maxP  = avgP + 256;
    float* scaleP = maxP + 256;

    qkv2_kernel<<<dim3(N_ / 128, B_), 256, 0, stream>>>(x, wq, bq, wk, bk, wv, bv, Qt, Kt, Vp);
    attn_kernel<<<dim3(N_ / 128, MSPLIT, B_), 256, 0, stream>>>(Qt, Kt, Vp, part);
    reduce_pool<<<dim3(C_, B_), 256, 0, stream>>>(part, x, outp, avgP, maxP);
    mlp_kernel<<<1, 256, 0, stream>>>(avgP, maxP, w1, w2, scaleP);
    scale_kernel<<<(B_ * C_ * N_ / 4) / 256, 256, 0, stream>>>(outp, scaleP);
}

// Round 11
// 201.240 us; speedup vs baseline: 1.1905x; 1.0468x over previous
//
#include <hip/hip_runtime.h>
#include <hip/hip_bf16.h>

#define B_  4
#define C_  64
#define N_  9216   // 96*96
#define BN  128
#define BM  64
#define NEG_LOG2E (-1.44269504088896340736f)

typedef _Float16 half8  __attribute__((ext_vector_type(8)));
typedef float    f32x16 __attribute__((ext_vector_type(16)));

static __device__ __forceinline__ float fast_exp2(float x){ float r; asm("v_exp_f32 %0, %1":"=v"(r):"v"(x)); return r; }
static __device__ __forceinline__ float fast_rcp (float x){ float r; asm("v_rcp_f32 %0, %1":"=v"(r):"v"(x)); return r; }

static __device__ __forceinline__ void gload16(const void* g, void* l){
    __builtin_amdgcn_global_load_lds((const __attribute__((address_space(1))) void*)g,
                                     (__attribute__((address_space(3))) void*)l, 16, 0, 0);
}

// sigmoid over 16 energies in place: att = 1/(1+2^s). Montgomery batch rcp:
// per 8 values, 1 v_rcp + 21 muls instead of 8 v_rcp (trans pipe is the bottleneck).
static __device__ __forceinline__ void sigmoid16(f32x16& s) {
    float d[16];
    #pragma unroll
    for (int r = 0; r < 16; ++r) d[r] = 1.f + fast_exp2(s[r]);
    #pragma unroll
    for (int g = 0; g < 16; g += 8) {
        const float p1 = d[g+0]*d[g+1], p2 = p1*d[g+2], p3 = p2*d[g+3];
        const float p4 = p3*d[g+4], p5 = p4*d[g+5], p6 = p5*d[g+6], p7 = p6*d[g+7];
        const float r7 = fast_rcp(p7);
        s[g+7] = r7*p6; const float r6 = r7*d[g+7];
        s[g+6] = r6*p5; const float r5 = r6*d[g+6];
        s[g+5] = r5*p4; const float r4 = r5*d[g+5];
        s[g+4] = r4*p3; const float r3 = r4*d[g+4];
        s[g+3] = r3*p2; const float r2 = r3*d[g+3];
        s[g+2] = r2*p1; const float r1 = r2*d[g+2];
        s[g+1] = r1*d[g+0];
        s[g+0] = r1*d[g+1];
    }
}

// ---------------- Kernel 0: fragment-ready W precompute ----------------
// Wprep[((mt*4+kk)*64 + lane)*8 + j] = W(o=mt*32+(lane&31), c=kk*16+(lane>>5)*8+j), Q rows pre-scaled
__global__ void prep_w(const float* __restrict__ wq, const float* __restrict__ wk,
                       const float* __restrict__ wv, _Float16* __restrict__ Wprep) {
    for (int t = threadIdx.x; t < 12 * 64 * 8; t += 256) {
        const int j = t & 7, lane = (t >> 3) & 63, g = t >> 9;
        const int kk = g & 3, mt = g >> 2;
        const int o = mt * 32 + (lane & 31);
        const int c = kk * 16 + (lane >> 5) * 8 + j;
        float v = 0.f;
        if (o < 8)       v = wq[o * C_ + c] * NEG_LOG2E;
        else if (o < 16) v = wk[(o - 8) * C_ + c];
        else if (o < 80) v = wv[(o - 16) * C_ + c];
        Wprep[t] = (_Float16)v;
    }
}

// ---------------- Kernel 1: QKV via MFMA ----------------
// grid (N/128, B), block 256; wave owns 32 n-cols, all 96 (80 used) out-rows
__global__ __launch_bounds__(256) void qkv2_kernel(
        const float* __restrict__ x, const _Float16* __restrict__ Wprep,
        const float* __restrict__ bq, const float* __restrict__ bk,
        const float* __restrict__ bv,
        _Float16* __restrict__ Qt, _Float16* __restrict__ Kt,
        _Float16* __restrict__ Vp) {
    const int tid = threadIdx.x;
    const int wv_i = tid >> 6, lane = tid & 63, l31 = lane & 31, hi = lane >> 5;
    const int b = blockIdx.y;
    const int n = blockIdx.x * 128 + wv_i * 32 + l31;

    half8 bf[4];
    #pragma unroll
    for (int kk = 0; kk < 4; ++kk) {
        half8 t;
        #pragma unroll
        for (int j = 0; j < 8; ++j) {
            const int c = kk * 16 + hi * 8 + j;
            t[j] = (_Float16)x[(size_t)(b * C_ + c) * N_ + n];
        }
        bf[kk] = t;
    }
    const int low = n & 15;
    const int g2 = (low >> 2) & 3;
    const int low2 = (g2 == 1) ? low + 4 : (g2 == 2) ? low - 4 : low;
    const int posn = (n & ~15) | low2;

    #pragma unroll
    for (int mt = 0; mt < 3; ++mt) {
        f32x16 acc = (f32x16)(0.f);
        #pragma unroll
        for (int kk = 0; kk < 4; ++kk) {
            const half8 af = *(const half8*)&Wprep[(((size_t)mt * 4 + kk) * 64 + lane) * 8];
            acc = __builtin_amdgcn_mfma_f32_32x32x16_f16(af, bf[kk], acc, 0, 0, 0);
        }
        #pragma unroll
        for (int r = 0; r < 16; ++r) {
            const int o = mt * 32 + (r & 3) + 8 * (r >> 2) + 4 * hi;
            if (o < 8)
                Qt[((size_t)(b * N_) + n) * 8 + o] = (_Float16)(acc[r] + bq[o] * NEG_LOG2E);
            else if (o < 16)
                Kt[((size_t)(b * N_) + n) * 8 + (o - 8)] = (_Float16)(acc[r] + bk[o - 8]);
            else if (o < 80)
                Vp[(size_t)(b * C_ + (o - 16)) * N_ + posn] = (_Float16)(acc[r] + bv[o - 16]);
        }
    }
}

// ---------------- Kernel 2: fused MFMA sigmoid-attention -> partials ----------------
// grid (N/128, MSP, B), block 256. VALIDATED round-4 structure; m-range templated.
#define VOFF 0
#define KOFF 16384
#define QOFF 18432
#define ZOFF 20480
#define LDSBYTES 20608

#define STAGE(mt, bsel) do {                                                            \
    const int m0s_ = mbase + (mt) * 64;                                                 \
    if (wave == 0)                                                                      \
        gload16(Kt + ((size_t)(b * N_ + m0s_) + lane) * 8, lds + KOFF + (bsel) * 1024); \
    {                                                                                   \
        const int ld0_ = wave * 2;                                                      \
        const int cl0_ = ld0_ * 8 + (lane >> 3);                                        \
        const int q0_  = (lane & 7) ^ (cl0_ & 7);                                       \
        gload16(Vp + (size_t)(b * C_ + cl0_) * N_ + m0s_ + q0_ * 8,                     \
                lds + VOFF + (bsel) * 8192 + ld0_ * 1024);                              \
        const int cl1_ = cl0_ + 8;                                                      \
        const int q1_  = (lane & 7) ^ (cl1_ & 7);                                       \
        gload16(Vp + (size_t)(b * C_ + cl1_) * N_ + m0s_ + q1_ * 8,                     \
                lds + VOFF + (bsel) * 8192 + (ld0_ + 1) * 1024);                        \
    } } while (0)

template <int MSP>
__global__ __launch_bounds__(256) void attn_kernel(
        const _Float16* __restrict__ Qt, const _Float16* __restrict__ Kt,
        const _Float16* __restrict__ Vp, float* __restrict__ part) {
    constexpr int MCHUNK = N_ / MSP;
    constexpr int NITER  = MCHUNK / BM;
    __shared__ ulong2 ldsq[LDSBYTES / 16];
    char* lds = (char*)ldsq;
    const int tid  = threadIdx.x;
    const int wave = tid >> 6, lane = tid & 63;
    const int l31  = lane & 31;
    const int hi   = lane >> 5;
    const int b    = blockIdx.z, mh = blockIdx.y;
    const int n0   = blockIdx.x * 128;
    const int mbase = mh * MCHUNK;

    if (tid < 8) ((short*)(lds + ZOFF))[tid] = 0;

    STAGE(0, 0);
    if (wave == 1) {
        gload16(Qt + ((size_t)(b * N_ + n0) + lane) * 8,      lds + QOFF);
        gload16(Qt + ((size_t)(b * N_ + n0 + 64) + lane) * 8, lds + QOFF + 1024);
    }
    __syncthreads();

    const int qa = (lane < 32) ? (QOFF + (wave * 32 + l31) * 16) : ZOFF;
    const half8 qf = *(const half8*)(lds + qa);

    f32x16 acc0 = (f32x16)(0.f), acc1 = (f32x16)(0.f);

    for (int t = 0; t < NITER; ++t) {
        const int buf = t & 1;
        if (t + 1 < NITER) STAGE(t + 1, buf ^ 1);

        const int ka0 = (lane < 32) ? (KOFF + buf * 1024 +       l31 * 16) : ZOFF;
        const int ka1 = (lane < 32) ? (KOFF + buf * 1024 + 512 + l31 * 16) : ZOFF;
        const half8 kf0 = *(const half8*)(lds + ka0);
        const half8 kf1 = *(const half8*)(lds + ka1);
        f32x16 s0 = __builtin_amdgcn_mfma_f32_32x32x16_f16(kf0, qf, (f32x16)(0.f), 0, 0, 0);
        f32x16 s1 = __builtin_amdgcn_mfma_f32_32x32x16_f16(kf1, qf, (f32x16)(0.f), 0, 0, 0);

        sigmoid16(s0);
        sigmoid16(s1);

        const int vbase = VOFF + buf * 8192;
        #pragma unroll
        for (int ks = 0; ks < 4; ++ks) {
            f32x16 am = (ks < 2) ? s0 : s1;
            const int bb = (ks & 1) * 8;
            uint4 pk;
            pk.x = __builtin_bit_cast(unsigned int, __builtin_amdgcn_cvt_pkrtz(am[bb + 0], am[bb + 1]));
            pk.y = __builtin_bit_cast(unsigned int, __builtin_amdgcn_cvt_pkrtz(am[bb + 2], am[bb + 3]));
            pk.z = __builtin_bit_cast(unsigned int, __builtin_amdgcn_cvt_pkrtz(am[bb + 4], am[bb + 5]));
            pk.w = __builtin_bit_cast(unsigned int, __builtin_amdgcn_cvt_pkrtz(am[bb + 6], am[bb + 7]));
            const half8 bf = __builtin_bit_cast(half8, pk);
            const int sw = ((2 * ks + hi) ^ (l31 & 7)) * 16;
            const half8 af0 = *(const half8*)(lds + vbase + l31 * 128 + sw);
            const half8 af1 = *(const half8*)(lds + vbase + (32 + l31) * 128 + sw);
            acc0 = __builtin_amdgcn_mfma_f32_32x32x16_f16(af0, bf, acc0, 0, 0, 0);
            acc1 = __builtin_amdgcn_mfma_f32_32x32x16_f16(af1, bf, acc1, 0, 0, 0);
        }
        __syncthreads();
    }

    float* pp = part + ((size_t)(mh * B_ + b) * C_) * (size_t)N_ + n0 + wave * 32 + l31;
    #pragma unroll
    for (int r = 0; r < 16; ++r) {
        const int c0 = (r & 3) + 8 * (r >> 2) + 4 * hi;
        pp[(size_t)c0 * N_]        = acc0[r];
        pp[(size_t)(c0 + 32) * N_] = acc1[r];
    }
}

// ---------------- Kernel 3: partials + residual -> out, fused avg/max pool ----------------
template <int MSP>
__global__ void reduce_pool(const float* __restrict__ part, const float* __restrict__ x,
                            float* __restrict__ outp,
                            float* __restrict__ avgP, float* __restrict__ maxP) {
    const int c = blockIdx.x, b = blockIdx.y;
    const size_t off = (size_t)(b * C_ + c) * N_;
    const float4* xr = (const float4*)(x + off);
    float4* orow = (float4*)(outp + off);
    const int tid = threadIdx.x;
    float s = 0.f, mx = -3.4e38f;
    for (int i = tid; i < N_ / 4; i += 256) {
        float4 o = xr[i];
        #pragma unroll
        for (int m = 0; m < MSP; ++m) {
            const float4 p = ((const float4*)(part + ((size_t)(m * B_ + b) * C_ + c) * N_))[i];
            o.x += p.x; o.y += p.y; o.z += p.z; o.w += p.w;
        }
        orow[i] = o;
        s += o.x + o.y + o.z + o.w;
        mx = fmaxf(mx, fmaxf(fmaxf(o.x, o.y), fmaxf(o.z, o.w)));
    }
    #pragma unroll
    for (int offm = 32; offm > 0; offm >>= 1) {
        s += __shfl_down(s, offm, 64);
        mx = fmaxf(mx, __shfl_down(mx, offm, 64));
    }
    __shared__ float ss[4], sm[4];
    if ((tid & 63) == 0) { ss[tid >> 6] = s; sm[tid >> 6] = mx; }
    __syncthreads();
    if (tid == 0) {
        float fs = ss[0] + ss[1] + ss[2] + ss[3];
        float fm = fmaxf(fmaxf(sm[0], sm[1]), fmaxf(sm[2], sm[3]));
        avgP[b * C_ + c] = fs / (float)N_;
        maxP[b * C_ + c] = fm;
    }
}

// ---------------- Kernel 4: CBAM MLP + sigmoid scale ----------------
__global__ void mlp_kernel(const float* __restrict__ avgP, const float* __restrict__ maxP,
                           const float* __restrict__ w1, const float* __restrict__ w2,
                           float* __restrict__ scaleP) {
    __shared__ float h[32];
    const int tid = threadIdx.x;
    if (tid < 32) {
        int b = tid >> 3, r = (tid >> 1) & 3, wh = tid & 1;
        const float* src = wh ? maxP : avgP;
        float s = 0.f;
        for (int c = 0; c < C_; ++c) s += src[b * C_ + c] * w1[r * C_ + c];
        h[tid] = fmaxf(s, 0.f);
    }
    __syncthreads();
    int b = tid >> 6, c = tid & 63;
    float s = 0.f;
    #pragma unroll
    for (int r = 0; r < 4; ++r)
        s += (h[b * 8 + r * 2] + h[b * 8 + r * 2 + 1]) * w2[c * 4 + r];
    scaleP[tid] = fast_rcp(1.f + fast_exp2(s * NEG_LOG2E));
}

// ---------------- Kernel 5: apply channel scale in place ----------------
__global__ void scale_kernel(float* __restrict__ outp, const float* __restrict__ scaleP) {
    int i4 = blockIdx.x * 256 + threadIdx.x;
    float sc = scaleP[i4 / (N_ / 4)];
    float4 v = *(const float4*)&outp[(size_t)i4 * 4];
    v.x *= sc; v.y *= sc; v.z *= sc; v.w *= sc;
    *(float4*)&outp[(size_t)i4 * 4] = v;
}

extern "C" void kernel_launch(void* const* d_in, const int* in_sizes, int n_in,
                              void* d_out, int out_size, void* d_ws, size_t ws_size,
                              hipStream_t stream) {
    const float* x  = (const float*)d_in[0];
    const float* wq = (const float*)d_in[1];
    const float* bq = (const float*)d_in[2];
    const float* wk = (const float*)d_in[3];
    const float* bk = (const float*)d_in[4];
    const float* wv = (const float*)d_in[5];
    const float* bv = (const float*)d_in[6];
    const float* w1 = (const float*)d_in[7];
    const float* w2 = (const float*)d_in[8];
    float* outp = (float*)d_out;

    char* w = (char*)d_ws;
    _Float16* Qt = (_Float16*)(w);                       // 589824 B
    _Float16* Kt = (_Float16*)(w + 589824);              // 589824 B
    _Float16* Vp = (_Float16*)(w + 1179648);             // 4718592 B
    float* part  = (float*)(w + 5898240);
    const size_t PART1 = (size_t)B_ * C_ * N_ * 4;       // 9437184 B per slice

    // MSPLIT=8 if workspace allows, else the silicon-validated 4.
    const int msp = (ws_size >= 5898240 + 8 * PART1 + 16384) ? 8 : 4;
    char* tail = w + 5898240 + (size_t)msp * PART1;
    float* avgP = (float*)tail;
    float* maxP = avgP + 256;
    float* scaleP = maxP + 256;
    _Float16* Wprep = (_Float16*)(tail + 3072);          // 12288 B

    prep_w<<<1, 256, 0, stream>>>(wq, wk, wv, Wprep);
    qkv2_kernel<<<dim3(N_ / 128, B_), 256, 0, stream>>>(x, Wprep, bq, bk, bv, Qt, Kt, Vp);
    if (msp == 8) {
        attn_kernel<8><<<dim3(N_ / 128, 8, B_), 256, 0, stream>>>(Qt, Kt, Vp, part);
        reduce_pool<8><<<dim3(C_, B_), 256, 0, stream>>>(part, x, outp, avgP, maxP);
    } else {
        attn_kernel<4><<<dim3(N_ / 128, 4, B_), 256, 0, stream>>>(Qt, Kt, Vp, part);
        reduce_pool<4><<<dim3(C_, B_), 256, 0, stream>>>(part, x, outp, avgP, maxP);
    }
    mlp_kernel<<<1, 256, 0, stream>>>(avgP, maxP, w1, w2, scaleP);
    scale_kernel<<<(B_ * C_ * N_ / 4) / 256, 256, 0, stream>>>(outp, scaleP);
}